// Round 7
// baseline (99.376 us; speedup 1.0000x reference)
//
#include <hip/hip_runtime.h>
#include <hip/hip_bf16.h>

// ---------------------------------------------------------------------------
// Attention_53223234732453: B=16, C=128, H=W=32 -> N=1024, HEADS=4, d=32
// R7: attn grid 512 -> 1024 blocks (i-tile 64, one Q-frag per wave):
//     4 blocks/CU, 4 waves/SIMD to cover L2/DS latency (R1 counters showed
//     VALUBusy 43%/Occ 25% at 2 waves/SIMD -- stall-bound, not pipe-bound).
//     All verified machinery retained: bias-free exp2 softmax (log2e folded
//     into q-scale), S^T operand swap, b64 pT writes, per-lane l, prefetch.
// qkv_kernel identical to R6 (verified).
// ---------------------------------------------------------------------------

typedef __bf16 bf16x8 __attribute__((ext_vector_type(8)));
typedef float  f32x4  __attribute__((ext_vector_type(4)));

__device__ __forceinline__ unsigned short f2bf(float f) {
    union { float f; unsigned int u; } v; v.f = f;
    return (unsigned short)((v.u + 0x7FFFu + ((v.u >> 16) & 1u)) >> 16);
}

__device__ __forceinline__ unsigned int pkbf2(float a, float b) {
    union { __hip_bfloat162 h; unsigned int u; } cv;
    cv.h = __float22bfloat162_rn(float2{a, b});  // x -> bits[15:0], y -> [31:16]
    return cv.u;
}

// ---------------------------------------------------------------------------
// K1: qkv = W @ x (W converted fp32->bf16 in-block; q rows scaled by
// d^-0.5 * log2e). grid = 16 b x 16 n-tiles(64), 512 thr (8 waves).
// Wave tile 48o x 64n. All 16 x-loads + 24 W-loads in flight, ONE barrier.
// Epilogue (verified): uint2 C-layout stores for Q/K; V via per-wave LDS
// transpose (stride 17) into tiled Vt2[bh][jblk][d][j&7].
// ---------------------------------------------------------------------------
__global__ __launch_bounds__(512)
void qkv_kernel(const float* __restrict__ x, const float* __restrict__ W,
                const float* __restrict__ rw, const float* __restrict__ rh,
                unsigned short* __restrict__ Qs, unsigned short* __restrict__ Kr,
                unsigned short* __restrict__ Vt2)
{
    __shared__ unsigned short Xs[16 * 520];      // 128c x 64n tile, B-frag layout
    __shared__ unsigned short Ls[3][64 * 17];    // V transpose buffers (waves 5..7)

    const int b  = blockIdx.x >> 4;
    const int n0 = (blockIdx.x & 15) << 6;
    const int t  = threadIdx.x;
    const int w  = t >> 6;                       // wave 0..7 -> o = w*48 ..
    const int lane = t & 63;
    const int col = lane & 15, quad = lane >> 4;

    const int cl = t >> 6;                       // staging: c sub-row 0..7
    const int ns = t & 63;                       // staging: n 0..63

    // all 16 x loads in flight together (one HBM latency)
    float xv[4][4];
    #pragma unroll
    for (int ks = 0; ks < 4; ++ks)
        #pragma unroll
        for (int p = 0; p < 4; ++p)
            xv[ks][p] = x[(((size_t)(b * 128 + ks * 32 + p * 8 + cl)) << 10) + n0 + ns];

    // W fp32 -> A-frags in registers (q rows pre-scaled by d^-0.5*log2e)
    bf16x8 af[4][3];
    #pragma unroll
    for (int a = 0; a < 3; ++a) {
        const int o = w * 48 + a * 16 + col;
        const float sc = (w * 48 + a * 16 < 128) ? 0.25503527f : 1.0f;
        #pragma unroll
        for (int ks = 0; ks < 4; ++ks) {
            const float4 w0 = *(const float4*)&W[o * 128 + ks * 32 + quad * 8];
            const float4 w1 = *(const float4*)&W[o * 128 + ks * 32 + quad * 8 + 4];
            union { unsigned int u[4]; bf16x8 v; } cv;
            cv.u[0] = pkbf2(w0.x * sc, w0.y * sc);
            cv.u[1] = pkbf2(w0.z * sc, w0.w * sc);
            cv.u[2] = pkbf2(w1.x * sc, w1.y * sc);
            cv.u[3] = pkbf2(w1.z * sc, w1.w * sc);
            af[ks][a] = cv.v;
        }
    }

    #pragma unroll
    for (int ks = 0; ks < 4; ++ks)
        #pragma unroll
        for (int p = 0; p < 4; ++p)
            Xs[(ks * 4 + p) * 520 + ns * 8 + cl] = f2bf(xv[ks][p]);
    __syncthreads();

    f32x4 acc[3][4];
    #pragma unroll
    for (int a = 0; a < 3; ++a)
        #pragma unroll
        for (int t4 = 0; t4 < 4; ++t4)
            acc[a][t4] = (f32x4){0.f, 0.f, 0.f, 0.f};

    #pragma unroll
    for (int ks = 0; ks < 4; ++ks)
        #pragma unroll
        for (int t4 = 0; t4 < 4; ++t4) {
            const bf16x8 bfr = *(const bf16x8*)&Xs[(ks * 4 + quad) * 520 + (t4 * 16 + col) * 8];
            #pragma unroll
            for (int a = 0; a < 3; ++a)
                acc[a][t4] = __builtin_amdgcn_mfma_f32_16x16x32_bf16(af[ks][a], bfr, acc[a][t4], 0, 0, 0);
        }

    // ---- epilogue (verified) ----
    #pragma unroll
    for (int a = 0; a < 3; ++a) {
        const int og = w * 48 + a * 16;          // multiple of 16
        const int s  = og >> 7;
        const int h  = (og >> 5) & 3;
        const int bh = (b << 2) + h;
        const int dd0 = og & 31;

        if (s == 0) {                            // Q: direct uint2 stores
            #pragma unroll
            for (int t4 = 0; t4 < 4; ++t4) {
                const int n = n0 + (t4 << 4) + col;
                union { unsigned short u[4]; uint2 v; } pk;
                #pragma unroll
                for (int r = 0; r < 4; ++r) pk.u[r] = f2bf(acc[a][t4][r]);
                *(uint2*)&Qs[(((bh << 10) + n) << 5) + dd0 + (quad << 2)] = pk.v;
            }
        } else if (s == 1) {                     // K: add rw+rh, uint2 stores
            #pragma unroll
            for (int t4 = 0; t4 < 4; ++t4) {
                const int n = n0 + (t4 << 4) + col;
                const int nw = n & 31, nh = n >> 5;
                union { unsigned short u[4]; uint2 v; } pk;
                #pragma unroll
                for (int r = 0; r < 4; ++r) {
                    const int dd = dd0 + (quad << 2) + r;
                    const float rv = rw[((h << 5) + dd) * 32 + nw]
                                   + rh[((h << 5) + dd) * 32 + nh];
                    pk.u[r] = f2bf(acc[a][t4][r] + rv);
                }
                *(uint2*)&Kr[(((bh << 10) + n) << 5) + dd0 + (quad << 2)] = pk.v;
            }
        } else {                                 // V: LDS transpose -> Vt2
            unsigned short* Lw = Ls[w - 5];
            #pragma unroll
            for (int t4 = 0; t4 < 4; ++t4)
                #pragma unroll
                for (int r = 0; r < 4; ++r)
                    Lw[((t4 << 4) + col) * 17 + (quad << 2) + r] = f2bf(acc[a][t4][r]);
            // same-wave DS ordering: no barrier needed
            const int ddl = lane & 15;           // group-local o
            const int no2 = lane >> 4;           // 0..3
            #pragma unroll
            for (int uu = 0; uu < 2; ++uu) {
                const int no = (uu << 2) + no2;  // 8-j octet 0..7
                union { unsigned short u[8]; uint4 v; } pk;
                #pragma unroll
                for (int k = 0; k < 8; ++k)
                    pk.u[k] = Lw[((no << 3) + k) * 17 + ddl];
                const int jb = (n0 >> 3) + no;
                *(uint4*)&Vt2[(bh << 15) + (((jb << 5) + dd0 + ddl) << 3)] = pk.v;
            }
        }
    }
}

// ---------------------------------------------------------------------------
// K2: attention. grid = 64 bh x 16 i-tiles(64) = 1024 blocks, 256 thr
// (4 waves; 4 blocks/CU -> 4 waves/SIMD). Wave owns 16 i (ONE Q-frag).
// Bias-free: p = exp2(s); constant cancels in (P.V)/l. S^T via operand
// swap (lane: i=col, j=t4*16+quad*4+r); P packed v_cvt_pk_bf16_f32,
// b64 LDS writes; PV B-frags b128; l per-lane, shfl_xor(16/32) at end.
// ---------------------------------------------------------------------------
__global__ __launch_bounds__(256)
void attn_kernel(const unsigned short* __restrict__ Qs,
                 const unsigned short* __restrict__ Kr,
                 const unsigned short* __restrict__ Vt2,
                 float* __restrict__ out)
{
    __shared__ unsigned short pT[4][16 * 72];    // [wave][i][j(+pad)]

    const int bh = blockIdx.x >> 4;
    const int i0 = (blockIdx.x & 15) << 6;
    const int t  = threadIdx.x;
    const int w  = t >> 6, lane = t & 63;
    const int col = lane & 15, quad = lane >> 4;
    const int iw = i0 + (w << 4);                // this wave's 16 i-rows

    const int base = bh << 15;                   // elem base for Qs/Kr/Vt2

    const bf16x8 qf = *(const bf16x8*)&Qs[base + ((iw + col) << 5) + (quad << 3)];

    const f32x4 zero = {0.f, 0.f, 0.f, 0.f};
    f32x4 oacc[2] = {zero, zero};
    float lacc = 0.f;

    bf16x8 kb[4], va[2], vb[2];
    #pragma unroll
    for (int t4 = 0; t4 < 4; ++t4)
        kb[t4] = *(const bf16x8*)&Kr[base + (((t4 << 4) + col) << 5) + (quad << 3)];
    #pragma unroll
    for (int jh = 0; jh < 2; ++jh) {
        va[jh] = *(const bf16x8*)&Vt2[base + ((((jh << 2) + quad) << 5) + col) * 8];
        vb[jh] = *(const bf16x8*)&Vt2[base + ((((jh << 2) + quad) << 5) + col + 16) * 8];
    }

    #pragma unroll 1
    for (int jt = 0; jt < 16; ++jt) {
        // S^T tiles: D[j = t4*16 + quad*4 + r][i = col]
        f32x4 s[4];
        #pragma unroll
        for (int t4 = 0; t4 < 4; ++t4)
            s[t4] = __builtin_amdgcn_mfma_f32_16x16x32_bf16(kb[t4], qf, zero, 0, 0, 0);

        // prefetch next jt's K and V frags (latency hidden by exp chain)
        const int jn = (jt + 1) & 15;
        bf16x8 kbn[4], van[2], vbn[2];
        #pragma unroll
        for (int t4 = 0; t4 < 4; ++t4)
            kbn[t4] = *(const bf16x8*)&Kr[base + (((jn << 6) + (t4 << 4) + col) << 5) + (quad << 3)];
        #pragma unroll
        for (int jh = 0; jh < 2; ++jh) {
            const int jblk = (jn << 3) + (jh << 2) + quad;
            van[jh] = *(const bf16x8*)&Vt2[base + ((jblk << 5) + col) * 8];
            vbn[jh] = *(const bf16x8*)&Vt2[base + ((jblk << 5) + col + 16) * 8];
        }

        // p = exp2(s) (no bias; constant cancels in PV/l); pack -> b64 LDS
        #pragma unroll
        for (int t4 = 0; t4 < 4; ++t4) {
            const float p0 = __builtin_amdgcn_exp2f(s[t4][0]);
            const float p1 = __builtin_amdgcn_exp2f(s[t4][1]);
            const float p2 = __builtin_amdgcn_exp2f(s[t4][2]);
            const float p3 = __builtin_amdgcn_exp2f(s[t4][3]);
            lacc += (p0 + p1) + (p2 + p3);
            uint2 pk;
            pk.x = pkbf2(p0, p1);
            pk.y = pkbf2(p2, p3);
            *(uint2*)&pT[w][col * 72 + (t4 << 4) + (quad << 2)] = pk;
        }

        // PV: O[d][i] += V[d][j] * P^T[j][i]; B-frag = P[i=col][j 8-run]
        #pragma unroll
        for (int jh = 0; jh < 2; ++jh) {
            const bf16x8 p0 = *(const bf16x8*)&pT[w][col * 72 + (jh << 5) + (quad << 3)];
            oacc[0] = __builtin_amdgcn_mfma_f32_16x16x32_bf16(va[jh], p0, oacc[0], 0, 0, 0);
            oacc[1] = __builtin_amdgcn_mfma_f32_16x16x32_bf16(vb[jh], p0, oacc[1], 0, 0, 0);
        }

        #pragma unroll
        for (int t4 = 0; t4 < 4; ++t4) kb[t4] = kbn[t4];
        #pragma unroll
        for (int jh = 0; jh < 2; ++jh) { va[jh] = van[jh]; vb[jh] = vbn[jh]; }
    }

    // epilogue: l reduce across quads (j partials); O[d][i] / l[i]
    const int b = bh >> 2, h = bh & 3;
    float v = lacc;
    v += __shfl_xor(v, 16);
    v += __shfl_xor(v, 32);
    const float linv = 1.0f / v;                 // l for i = iw + col
    #pragma unroll
    for (int dh = 0; dh < 2; ++dh)
        #pragma unroll
        for (int r = 0; r < 4; ++r) {
            const int d = (dh << 4) + (quad << 2) + r;
            out[(((size_t)(b * 128 + (h << 5) + d)) << 10) + iw + col]
                = oacc[dh][r] * linv;
        }
}

extern "C" void kernel_launch(void* const* d_in, const int* in_sizes, int n_in,
                              void* d_out, int out_size, void* d_ws, size_t ws_size,
                              hipStream_t stream)
{
    const float* x  = (const float*)d_in[0];
    const float* Wq = (const float*)d_in[1];
    const float* rw = (const float*)d_in[2];
    const float* rh = (const float*)d_in[3];
    float* out = (float*)d_out;

    const size_t elems = (size_t)16 * 4 * 1024 * 32;   // 2M bf16 per tensor
    unsigned short* Qs  = (unsigned short*)d_ws;
    unsigned short* Kr  = Qs + elems;
    unsigned short* Vt2 = Kr + elems;

    qkv_kernel<<<256, 512, 0, stream>>>(x, Wq, rw, rh, Qs, Kr, Vt2);
    attn_kernel<<<1024, 256, 0, stream>>>(Qs, Kr, Vt2, out);
}

// Round 8
// 94.253 us; speedup vs baseline: 1.0543x; 1.0543x over previous
//
#include <hip/hip_runtime.h>
#include <hip/hip_bf16.h>

// ---------------------------------------------------------------------------
// Attention_53223234732453: B=16, C=128, H=W=32 -> N=1024, HEADS=4, d=32
// R8: R6 base (best: 512 attn blocks, 2 Q-frags/wave). attn-only change:
//     (a) pT double-buffered by jt parity -- kills the WAR stall between
//         jt's pT reads and jt+1's pT writes;
//     (b) #pragma unroll 2 on the jt loop so the compiler overlaps jt+1's
//         S-MFMA/exp chain with jt's PV tail (K/V prefetched 1 iter ahead).
// qkv_kernel identical to R6 (verified). Bias-free exp2 softmax retained.
// ---------------------------------------------------------------------------

typedef __bf16 bf16x8 __attribute__((ext_vector_type(8)));
typedef float  f32x4  __attribute__((ext_vector_type(4)));

__device__ __forceinline__ unsigned short f2bf(float f) {
    union { float f; unsigned int u; } v; v.f = f;
    return (unsigned short)((v.u + 0x7FFFu + ((v.u >> 16) & 1u)) >> 16);
}

__device__ __forceinline__ unsigned int pkbf2(float a, float b) {
    union { __hip_bfloat162 h; unsigned int u; } cv;
    cv.h = __float22bfloat162_rn(float2{a, b});  // x -> bits[15:0], y -> [31:16]
    return cv.u;
}

// ---------------------------------------------------------------------------
// K1: qkv = W @ x (W converted fp32->bf16 in-block; q rows scaled by
// d^-0.5 * log2e). grid = 16 b x 16 n-tiles(64), 512 thr (8 waves).
// Wave tile 48o x 64n. All 16 x-loads + 24 W-loads in flight, ONE barrier.
// Epilogue (verified): uint2 C-layout stores for Q/K; V via per-wave LDS
// transpose (stride 17) into tiled Vt2[bh][jblk][d][j&7].
// ---------------------------------------------------------------------------
__global__ __launch_bounds__(512)
void qkv_kernel(const float* __restrict__ x, const float* __restrict__ W,
                const float* __restrict__ rw, const float* __restrict__ rh,
                unsigned short* __restrict__ Qs, unsigned short* __restrict__ Kr,
                unsigned short* __restrict__ Vt2)
{
    __shared__ unsigned short Xs[16 * 520];      // 128c x 64n tile, B-frag layout
    __shared__ unsigned short Ls[3][64 * 17];    // V transpose buffers (waves 5..7)

    const int b  = blockIdx.x >> 4;
    const int n0 = (blockIdx.x & 15) << 6;
    const int t  = threadIdx.x;
    const int w  = t >> 6;                       // wave 0..7 -> o = w*48 ..
    const int lane = t & 63;
    const int col = lane & 15, quad = lane >> 4;

    const int cl = t >> 6;                       // staging: c sub-row 0..7
    const int ns = t & 63;                       // staging: n 0..63

    // all 16 x loads in flight together (one HBM latency)
    float xv[4][4];
    #pragma unroll
    for (int ks = 0; ks < 4; ++ks)
        #pragma unroll
        for (int p = 0; p < 4; ++p)
            xv[ks][p] = x[(((size_t)(b * 128 + ks * 32 + p * 8 + cl)) << 10) + n0 + ns];

    // W fp32 -> A-frags in registers (q rows pre-scaled by d^-0.5*log2e)
    bf16x8 af[4][3];
    #pragma unroll
    for (int a = 0; a < 3; ++a) {
        const int o = w * 48 + a * 16 + col;
        const float sc = (w * 48 + a * 16 < 128) ? 0.25503527f : 1.0f;
        #pragma unroll
        for (int ks = 0; ks < 4; ++ks) {
            const float4 w0 = *(const float4*)&W[o * 128 + ks * 32 + quad * 8];
            const float4 w1 = *(const float4*)&W[o * 128 + ks * 32 + quad * 8 + 4];
            union { unsigned int u[4]; bf16x8 v; } cv;
            cv.u[0] = pkbf2(w0.x * sc, w0.y * sc);
            cv.u[1] = pkbf2(w0.z * sc, w0.w * sc);
            cv.u[2] = pkbf2(w1.x * sc, w1.y * sc);
            cv.u[3] = pkbf2(w1.z * sc, w1.w * sc);
            af[ks][a] = cv.v;
        }
    }

    #pragma unroll
    for (int ks = 0; ks < 4; ++ks)
        #pragma unroll
        for (int p = 0; p < 4; ++p)
            Xs[(ks * 4 + p) * 520 + ns * 8 + cl] = f2bf(xv[ks][p]);
    __syncthreads();

    f32x4 acc[3][4];
    #pragma unroll
    for (int a = 0; a < 3; ++a)
        #pragma unroll
        for (int t4 = 0; t4 < 4; ++t4)
            acc[a][t4] = (f32x4){0.f, 0.f, 0.f, 0.f};

    #pragma unroll
    for (int ks = 0; ks < 4; ++ks)
        #pragma unroll
        for (int t4 = 0; t4 < 4; ++t4) {
            const bf16x8 bfr = *(const bf16x8*)&Xs[(ks * 4 + quad) * 520 + (t4 * 16 + col) * 8];
            #pragma unroll
            for (int a = 0; a < 3; ++a)
                acc[a][t4] = __builtin_amdgcn_mfma_f32_16x16x32_bf16(af[ks][a], bfr, acc[a][t4], 0, 0, 0);
        }

    // ---- epilogue (verified) ----
    #pragma unroll
    for (int a = 0; a < 3; ++a) {
        const int og = w * 48 + a * 16;          // multiple of 16
        const int s  = og >> 7;
        const int h  = (og >> 5) & 3;
        const int bh = (b << 2) + h;
        const int dd0 = og & 31;

        if (s == 0) {                            // Q: direct uint2 stores
            #pragma unroll
            for (int t4 = 0; t4 < 4; ++t4) {
                const int n = n0 + (t4 << 4) + col;
                union { unsigned short u[4]; uint2 v; } pk;
                #pragma unroll
                for (int r = 0; r < 4; ++r) pk.u[r] = f2bf(acc[a][t4][r]);
                *(uint2*)&Qs[(((bh << 10) + n) << 5) + dd0 + (quad << 2)] = pk.v;
            }
        } else if (s == 1) {                     // K: add rw+rh, uint2 stores
            #pragma unroll
            for (int t4 = 0; t4 < 4; ++t4) {
                const int n = n0 + (t4 << 4) + col;
                const int nw = n & 31, nh = n >> 5;
                union { unsigned short u[4]; uint2 v; } pk;
                #pragma unroll
                for (int r = 0; r < 4; ++r) {
                    const int dd = dd0 + (quad << 2) + r;
                    const float rv = rw[((h << 5) + dd) * 32 + nw]
                                   + rh[((h << 5) + dd) * 32 + nh];
                    pk.u[r] = f2bf(acc[a][t4][r] + rv);
                }
                *(uint2*)&Kr[(((bh << 10) + n) << 5) + dd0 + (quad << 2)] = pk.v;
            }
        } else {                                 // V: LDS transpose -> Vt2
            unsigned short* Lw = Ls[w - 5];
            #pragma unroll
            for (int t4 = 0; t4 < 4; ++t4)
                #pragma unroll
                for (int r = 0; r < 4; ++r)
                    Lw[((t4 << 4) + col) * 17 + (quad << 2) + r] = f2bf(acc[a][t4][r]);
            // same-wave DS ordering: no barrier needed
            const int ddl = lane & 15;           // group-local o
            const int no2 = lane >> 4;           // 0..3
            #pragma unroll
            for (int uu = 0; uu < 2; ++uu) {
                const int no = (uu << 2) + no2;  // 8-j octet 0..7
                union { unsigned short u[8]; uint4 v; } pk;
                #pragma unroll
                for (int k = 0; k < 8; ++k)
                    pk.u[k] = Lw[((no << 3) + k) * 17 + ddl];
                const int jb = (n0 >> 3) + no;
                *(uint4*)&Vt2[(bh << 15) + (((jb << 5) + dd0 + ddl) << 3)] = pk.v;
            }
        }
    }
}

// ---------------------------------------------------------------------------
// K2: attention. grid = 64 bh x 8 i-tiles(128) = 512 blocks, 256 thr.
// Wave owns 32 i (2 Q frags g=0,1). Bias-free: p = exp2(s); constant
// cancels in (P.V)/l. S^T via operand swap (lane: i=col, j=t4*16+quad*4+r);
// P packed v_cvt_pk_bf16_f32, b64 LDS writes into parity-selected pT buffer
// (no WAR between consecutive jt); PV B-frags b128; unroll 2 lets the
// scheduler overlap jt+1's S/exp with jt's PV. l per-lane, shfl_xor at end.
// ---------------------------------------------------------------------------
__global__ __launch_bounds__(256)
void attn_kernel(const unsigned short* __restrict__ Qs,
                 const unsigned short* __restrict__ Kr,
                 const unsigned short* __restrict__ Vt2,
                 float* __restrict__ out)
{
    __shared__ unsigned short pT[2][4][2][16 * 72]; // [parity][wave][g][i][j+pad]

    const int bh = blockIdx.x >> 3;
    const int i0 = (blockIdx.x & 7) << 7;
    const int t  = threadIdx.x;
    const int w  = t >> 6, lane = t & 63;
    const int col = lane & 15, quad = lane >> 4;
    const int iw = i0 + (w << 5);

    const int base = bh << 15;                   // elem base for Qs/Kr/Vt2

    bf16x8 qf[2];
    #pragma unroll
    for (int g = 0; g < 2; ++g)
        qf[g] = *(const bf16x8*)&Qs[base + ((iw + (g << 4) + col) << 5) + (quad << 3)];

    const f32x4 zero = {0.f, 0.f, 0.f, 0.f};
    f32x4 oacc[2][2] = {{zero, zero}, {zero, zero}};
    float lacc[2] = {0.f, 0.f};

    bf16x8 kb[4], va[2], vb[2];
    #pragma unroll
    for (int t4 = 0; t4 < 4; ++t4)
        kb[t4] = *(const bf16x8*)&Kr[base + (((t4 << 4) + col) << 5) + (quad << 3)];
    #pragma unroll
    for (int jh = 0; jh < 2; ++jh) {
        va[jh] = *(const bf16x8*)&Vt2[base + ((((jh << 2) + quad) << 5) + col) * 8];
        vb[jh] = *(const bf16x8*)&Vt2[base + ((((jh << 2) + quad) << 5) + col + 16) * 8];
    }

    #pragma unroll 2
    for (int jt = 0; jt < 16; ++jt) {
        const int pb = jt & 1;                   // parity buffer (compile-time
                                                 // under unroll 2)
        // S^T tiles: D[j = t4*16 + quad*4 + r][i = col] per g
        f32x4 s[2][4];
        #pragma unroll
        for (int t4 = 0; t4 < 4; ++t4) {
            s[0][t4] = __builtin_amdgcn_mfma_f32_16x16x32_bf16(kb[t4], qf[0], zero, 0, 0, 0);
            s[1][t4] = __builtin_amdgcn_mfma_f32_16x16x32_bf16(kb[t4], qf[1], zero, 0, 0, 0);
        }

        // prefetch next jt's K and V frags (latency hidden by exp chain)
        const int jn = (jt + 1) & 15;
        bf16x8 kbn[4], van[2], vbn[2];
        #pragma unroll
        for (int t4 = 0; t4 < 4; ++t4)
            kbn[t4] = *(const bf16x8*)&Kr[base + (((jn << 6) + (t4 << 4) + col) << 5) + (quad << 3)];
        #pragma unroll
        for (int jh = 0; jh < 2; ++jh) {
            const int jblk = (jn << 3) + (jh << 2) + quad;
            van[jh] = *(const bf16x8*)&Vt2[base + ((jblk << 5) + col) * 8];
            vbn[jh] = *(const bf16x8*)&Vt2[base + ((jblk << 5) + col + 16) * 8];
        }

        // p = exp2(s) (no bias; constant cancels in PV/l); pack -> b64 LDS
        #pragma unroll
        for (int g = 0; g < 2; ++g) {
            #pragma unroll
            for (int t4 = 0; t4 < 4; ++t4) {
                const float p0 = __builtin_amdgcn_exp2f(s[g][t4][0]);
                const float p1 = __builtin_amdgcn_exp2f(s[g][t4][1]);
                const float p2 = __builtin_amdgcn_exp2f(s[g][t4][2]);
                const float p3 = __builtin_amdgcn_exp2f(s[g][t4][3]);
                lacc[g] += (p0 + p1) + (p2 + p3);
                uint2 pk;
                pk.x = pkbf2(p0, p1);
                pk.y = pkbf2(p2, p3);
                *(uint2*)&pT[pb][w][g][col * 72 + (t4 << 4) + (quad << 2)] = pk;
            }
        }

        // PV: O_g[d][i] += V[d][j] * P_g^T[j][i]; B-frag = P_g[i=col][j 8-run]
        #pragma unroll
        for (int jh = 0; jh < 2; ++jh) {
            const bf16x8 p0 = *(const bf16x8*)&pT[pb][w][0][col * 72 + (jh << 5) + (quad << 3)];
            const bf16x8 p1 = *(const bf16x8*)&pT[pb][w][1][col * 72 + (jh << 5) + (quad << 3)];
            oacc[0][0] = __builtin_amdgcn_mfma_f32_16x16x32_bf16(va[jh], p0, oacc[0][0], 0, 0, 0);
            oacc[0][1] = __builtin_amdgcn_mfma_f32_16x16x32_bf16(vb[jh], p0, oacc[0][1], 0, 0, 0);
            oacc[1][0] = __builtin_amdgcn_mfma_f32_16x16x32_bf16(va[jh], p1, oacc[1][0], 0, 0, 0);
            oacc[1][1] = __builtin_amdgcn_mfma_f32_16x16x32_bf16(vb[jh], p1, oacc[1][1], 0, 0, 0);
        }

        #pragma unroll
        for (int t4 = 0; t4 < 4; ++t4) kb[t4] = kbn[t4];
        #pragma unroll
        for (int jh = 0; jh < 2; ++jh) { va[jh] = van[jh]; vb[jh] = vbn[jh]; }
    }

    // epilogue: l reduce across quads (j partials); O[d][i] / l[i]
    const int b = bh >> 2, h = bh & 3;
    #pragma unroll
    for (int g = 0; g < 2; ++g) {
        float v = lacc[g];
        v += __shfl_xor(v, 16);
        v += __shfl_xor(v, 32);
        const float linv = 1.0f / v;             // l for i = iw + g*16 + col
        #pragma unroll
        for (int dh = 0; dh < 2; ++dh)
            #pragma unroll
            for (int r = 0; r < 4; ++r) {
                const int d = (dh << 4) + (quad << 2) + r;
                out[(((size_t)(b * 128 + (h << 5) + d)) << 10) + iw + (g << 4) + col]
                    = oacc[g][dh][r] * linv;
            }
    }
}

extern "C" void kernel_launch(void* const* d_in, const int* in_sizes, int n_in,
                              void* d_out, int out_size, void* d_ws, size_t ws_size,
                              hipStream_t stream)
{
    const float* x  = (const float*)d_in[0];
    const float* Wq = (const float*)d_in[1];
    const float* rw = (const float*)d_in[2];
    const float* rh = (const float*)d_in[3];
    float* out = (float*)d_out;

    const size_t elems = (size_t)16 * 4 * 1024 * 32;   // 2M bf16 per tensor
    unsigned short* Qs  = (unsigned short*)d_ws;
    unsigned short* Kr  = Qs + elems;
    unsigned short* Vt2 = Kr + elems;

    qkv_kernel<<<256, 512, 0, stream>>>(x, Wq, rw, rh, Qs, Kr, Vt2);
    attn_kernel<<<512, 256, 0, stream>>>(Qs, Kr, Vt2, out);
}